// Round 1
// baseline (1566.019 us; speedup 1.0000x reference)
//
#include <hip/hip_runtime.h>
#include <cstdint>
#include <cstddef>

typedef _Float16 half8 __attribute__((ext_vector_type(8)));
typedef _Float16 half4 __attribute__((ext_vector_type(4)));
typedef float    f32x4 __attribute__((ext_vector_type(4)));
typedef float    fvec4 __attribute__((ext_vector_type(4)));

#define DEV __device__ __forceinline__

constexpr int S_  = 729;
constexpr int D_  = 1152;
constexpr int H_  = 16;
constexpr int HD_ = 72;
constexpr int B_  = 16;
constexpr int M1  = B_ * S_;       // 11664
constexpr int SP  = 768;           // padded sequence
constexpr int HDP = 96;            // padded head dim (3 x K=32)
constexpr int QSTR = 104;          // row stride (f16) of q16/k16 (2-way-conflict-free)
constexpr float SCALE = 0.11785113019775793f;  // 72^-0.5

// ---- async global->LDS, 16B per lane -------------------------------------
DEV void gload16(const void* g, void* l) {
  typedef const __attribute__((address_space(1))) unsigned int GU;
  typedef __attribute__((address_space(3))) unsigned int LU;
  __builtin_amdgcn_global_load_lds((GU*)g, (LU*)l, 16, 0, 0);
}

// ---- f32 -> f16 conversion (vectorized) ----------------------------------
__global__ void cvt_f32_f16(const float* __restrict__ src, _Float16* __restrict__ dst, int n4) {
  int stride = gridDim.x * blockDim.x;
  for (int i = blockIdx.x * blockDim.x + threadIdx.x; i < n4; i += stride) {
    fvec4 v = ((const fvec4*)src)[i];
    half4 o;
    o[0] = (_Float16)v[0]; o[1] = (_Float16)v[1];
    o[2] = (_Float16)v[2]; o[3] = (_Float16)v[3];
    ((half4*)dst)[i] = o;
  }
}

// ---- K1: fused QKV projection GEMM  (M=11664, N=3456, K=1152) ------------
// A = h16 [M1][1152], W = wqkv16 [3456][1152] (row n is K-contiguous = W.T GEMM)
__global__ __launch_bounds__(256) void gemm_qkv(
    const _Float16* __restrict__ A, const _Float16* __restrict__ W,
    const float* __restrict__ qb, const float* __restrict__ kb, const float* __restrict__ vb,
    _Float16* __restrict__ q16, _Float16* __restrict__ k16, _Float16* __restrict__ vT16)
{
  __shared__ _Float16 lA[128 * 32];
  __shared__ _Float16 lB[128 * 32];
  const int tid  = threadIdx.x;
  const int wave = tid >> 6, lane = tid & 63;
  const int wr = wave >> 1, wc = wave & 1;
  const int l15 = lane & 15, l4 = lane >> 4;
  const int rowBase = blockIdx.y * 128;
  const int colBase = blockIdx.x * 128;

  f32x4 acc[4][4] = {};

  for (int kt = 0; kt < 36; ++kt) {
#pragma unroll
    for (int p = 0; p < 2; ++p) {
      int u = p * 256 + tid;
      int r = u >> 2, q = u & 3;
      int row = rowBase + r; if (row > M1 - 1) row = M1 - 1;   // tail clamp
      gload16(A + ((size_t)row * 1152 + kt * 32 + q * 8), &lA[u * 8]);
      gload16(W + ((size_t)(colBase + r) * 1152 + kt * 32 + q * 8), &lB[u * 8]);
    }
    __syncthreads();
    half8 af[4], bf[4];
#pragma unroll
    for (int i = 0; i < 4; ++i) {
      af[i] = *(const half8*)&lA[(wr * 64 + i * 16 + l15) * 32 + l4 * 8];
      bf[i] = *(const half8*)&lB[(wc * 64 + i * 16 + l15) * 32 + l4 * 8];
    }
#pragma unroll
    for (int mi = 0; mi < 4; ++mi)
#pragma unroll
      for (int ni = 0; ni < 4; ++ni)
        acc[mi][ni] = __builtin_amdgcn_mfma_f32_16x16x32_f16(af[mi], bf[ni], acc[mi][ni], 0, 0, 0);
    __syncthreads();
  }

  // epilogue: scatter into padded per-head layouts
  const int which = colBase / 1152;                 // 0=q 1=k 2=v (block-uniform, 1152=9*128)
  const int wi0 = colBase - which * 1152 + wc * 64;
  const float* bias = (which == 0) ? qb : (which == 1) ? kb : vb;
#pragma unroll
  for (int ni = 0; ni < 4; ++ni) {
    int wi = wi0 + ni * 16 + l15;
    int hh = wi / 72;
    int dd = wi - hh * 72;
    float bv = bias[wi];
#pragma unroll
    for (int mi = 0; mi < 4; ++mi) {
#pragma unroll
      for (int reg = 0; reg < 4; ++reg) {
        int m = rowBase + wr * 64 + mi * 16 + l4 * 4 + reg;
        if (m < M1) {
          float val = acc[mi][ni][reg] + bv;
          int b = m / 729;
          int s = m - b * 729;
          int bh = b * 16 + hh;
          if (which == 0)      q16[((size_t)bh * SP + s) * QSTR + dd] = (_Float16)val;
          else if (which == 1) k16[((size_t)bh * SP + s) * QSTR + dd] = (_Float16)val;
          else                 vT16[((size_t)bh * HDP + dd) * SP + s] = (_Float16)val;
        }
      }
    }
  }
}

// ---- K2: fused scores + softmax + attn-write + PV ------------------------
// grid: x = 23 row-blocks of 32, y = 256 (b*16+h)
__global__ __launch_bounds__(256) void attn_fused(
    const _Float16* __restrict__ q16, const _Float16* __restrict__ k16,
    const _Float16* __restrict__ vT16,
    float* __restrict__ attnOut,          // [256][729][729]
    _Float16* __restrict__ pv16)          // [M1][1152]
{
  __shared__ _Float16 sQ[32 * QSTR];      // 6656 B
  __shared__ _Float16 sK[128 * QSTR];     // 26624 B
  __shared__ float    sS[32 * 772];       // 98816 B  (stride 772: write 2-way, read 2-way)
  __shared__ float    sM[32];
  __shared__ float    sL[32];

  const int tid  = threadIdx.x;
  const int wave = tid >> 6, lane = tid & 63;
  const int l15 = lane & 15, l4 = lane >> 4;
  const int rb = blockIdx.x;
  const int bh = blockIdx.y;

  const _Float16* Qg = q16 + ((size_t)bh * SP + rb * 32) * QSTR;
  const _Float16* Kg = k16 + (size_t)bh * SP * QSTR;
  const _Float16* Vg = vT16 + (size_t)bh * HDP * SP;

  // stage Q block (32x104 f16 = 416 x 16B), contiguous in global
  for (int u = tid; u < 416; u += 256)
    gload16((const char*)Qg + u * 16, (char*)sQ + u * 16);

  // ---- scores: S[32][768] = Q * K^T * scale ----
  for (int ct = 0; ct < 6; ++ct) {
    for (int u = tid; u < 1664; u += 256)   // 128x104 f16 tile, contiguous
      gload16((const char*)Kg + (size_t)ct * 128 * QSTR * 2 + u * 16, (char*)sK + u * 16);
    __syncthreads();
    f32x4 acc[2][2] = {};
#pragma unroll
    for (int kk = 0; kk < 3; ++kk) {
      half8 a[2], bb[2];
#pragma unroll
      for (int i = 0; i < 2; ++i) {
        a[i]  = *(const half8*)&sQ[(i * 16 + l15) * QSTR + kk * 32 + l4 * 8];
        bb[i] = *(const half8*)&sK[(wave * 32 + i * 16 + l15) * QSTR + kk * 32 + l4 * 8];
      }
#pragma unroll
      for (int mi = 0; mi < 2; ++mi)
#pragma unroll
        for (int ni = 0; ni < 2; ++ni)
          acc[mi][ni] = __builtin_amdgcn_mfma_f32_16x16x32_f16(a[mi], bb[ni], acc[mi][ni], 0, 0, 0);
    }
#pragma unroll
    for (int mi = 0; mi < 2; ++mi)
#pragma unroll
      for (int ni = 0; ni < 2; ++ni)
#pragma unroll
        for (int reg = 0; reg < 4; ++reg)
          sS[(mi * 16 + l4 * 4 + reg) * 772 + ct * 128 + wave * 32 + ni * 16 + l15] =
              acc[mi][ni][reg] * SCALE;
    __syncthreads();
  }

  // ---- softmax stats: 8 consecutive lanes per row ----
  {
    int r = tid >> 3, j = tid & 7;
    const float* row = &sS[r * 772];
    float mx = -1e30f;
    for (int c = j; c < S_; c += 8) mx = fmaxf(mx, row[c]);
#pragma unroll
    for (int o = 1; o < 8; o <<= 1) mx = fmaxf(mx, __shfl_xor(mx, o));
    float sum = 0.f;
    for (int c = j; c < S_; c += 8) sum += __expf(row[c] - mx);
#pragma unroll
    for (int o = 1; o < 8; o <<= 1) sum += __shfl_xor(sum, o);
    if (j == 0) { sM[r] = mx; sL[r] = 1.0f / sum; }
  }
  __syncthreads();

  // ---- PV: out[32][96] = P[32][768] * V[768][96]; A-frags built on the fly ----
  {
    const int wm = wave >> 1, wn = wave & 1;
    const int arow = wm * 16 + l15;
    const float mrow = sM[arow];
    const float rl = sL[arow];
    f32x4 pacc[3] = {};
    for (int kk = 0; kk < 24; ++kk) {
      const float* sp = &sS[arow * 772 + kk * 32 + l4 * 8];
      half8 a;
#pragma unroll
      for (int t = 0; t < 8; ++t) a[t] = (_Float16)(__expf(sp[t] - mrow) * rl);
#pragma unroll
      for (int f = 0; f < 3; ++f) {
        const half8 bv = *(const half8*)(Vg + (size_t)(wn * 48 + f * 16 + l15) * SP + kk * 32 + l4 * 8);
        pacc[f] = __builtin_amdgcn_mfma_f32_16x16x32_f16(a, bv, pacc[f], 0, 0, 0);
      }
    }
    const int b = bh >> 4, h = bh & 15;
#pragma unroll
    for (int f = 0; f < 3; ++f) {
      int dd = wn * 48 + f * 16 + l15;
#pragma unroll
      for (int reg = 0; reg < 4; ++reg) {
        int srow = rb * 32 + wm * 16 + l4 * 4 + reg;
        if (dd < HD_ && srow < S_)
          pv16[((size_t)(b * 729 + srow)) * 1152 + h * 72 + dd] = (_Float16)pacc[f][reg];
      }
    }
  }

  // ---- attn output write (coalesced fp32 rows) ----
  {
    float* aout = attnOut + (size_t)bh * 531441 + (size_t)rb * 32 * 729;
    int vr = S_ - rb * 32; if (vr > 32) vr = 32;
    for (int r = 0; r < vr; ++r) {
      float mx = sM[r], rl = sL[r];
      const float* row = &sS[r * 772];
      for (int c = tid; c < S_; c += 256)
        aout[(size_t)r * 729 + c] = __expf(row[c] - mx) * rl;
    }
  }
}

// ---- K3: output projection GEMM (M=11664, N=1152, K=1152) -> fp32 out ----
__global__ __launch_bounds__(256) void gemm_out(
    const _Float16* __restrict__ A, const _Float16* __restrict__ W,
    const float* __restrict__ ob, float* __restrict__ Cout)
{
  __shared__ _Float16 lA[128 * 32];
  __shared__ _Float16 lB[128 * 32];
  const int tid  = threadIdx.x;
  const int wave = tid >> 6, lane = tid & 63;
  const int wr = wave >> 1, wc = wave & 1;
  const int l15 = lane & 15, l4 = lane >> 4;
  const int rowBase = blockIdx.y * 128;
  const int colBase = blockIdx.x * 128;

  f32x4 acc[4][4] = {};

  for (int kt = 0; kt < 36; ++kt) {
#pragma unroll
    for (int p = 0; p < 2; ++p) {
      int u = p * 256 + tid;
      int r = u >> 2, q = u & 3;
      int row = rowBase + r; if (row > M1 - 1) row = M1 - 1;
      gload16(A + ((size_t)row * 1152 + kt * 32 + q * 8), &lA[u * 8]);
      gload16(W + ((size_t)(colBase + r) * 1152 + kt * 32 + q * 8), &lB[u * 8]);
    }
    __syncthreads();
    half8 af[4], bf[4];
#pragma unroll
    for (int i = 0; i < 4; ++i) {
      af[i] = *(const half8*)&lA[(wr * 64 + i * 16 + l15) * 32 + l4 * 8];
      bf[i] = *(const half8*)&lB[(wc * 64 + i * 16 + l15) * 32 + l4 * 8];
    }
#pragma unroll
    for (int mi = 0; mi < 4; ++mi)
#pragma unroll
      for (int ni = 0; ni < 4; ++ni)
        acc[mi][ni] = __builtin_amdgcn_mfma_f32_16x16x32_f16(af[mi], bf[ni], acc[mi][ni], 0, 0, 0);
    __syncthreads();
  }

#pragma unroll
  for (int ni = 0; ni < 4; ++ni) {
    int n = colBase + wc * 64 + ni * 16 + l15;
    float bv = ob[n];
#pragma unroll
    for (int mi = 0; mi < 4; ++mi) {
#pragma unroll
      for (int reg = 0; reg < 4; ++reg) {
        int m = rowBase + wr * 64 + mi * 16 + l4 * 4 + reg;
        if (m < M1) Cout[(size_t)m * 1152 + n] = acc[mi][ni][reg] + bv;
      }
    }
  }
}

// --------------------------------------------------------------------------
extern "C" void kernel_launch(void* const* d_in, const int* in_sizes, int n_in,
                              void* d_out, int out_size, void* d_ws, size_t ws_size,
                              hipStream_t stream) {
  const float* hs = (const float*)d_in[0];
  const float* qw = (const float*)d_in[1];
  const float* qb = (const float*)d_in[2];
  const float* kw = (const float*)d_in[3];
  const float* kb = (const float*)d_in[4];
  const float* vw = (const float*)d_in[5];
  const float* vb = (const float*)d_in[6];
  const float* ow = (const float*)d_in[7];
  const float* ob = (const float*)d_in[8];

  char* ws = (char*)d_ws;
  size_t off = 0;
  auto alloc = [&](size_t bytes) {
    char* p = ws + off;
    off = (off + bytes + 255) & ~(size_t)255;
    return p;
  };
  _Float16* h16    = (_Float16*)alloc((size_t)M1 * D_ * 2);       // 26.9 MB
  _Float16* wqkv16 = (_Float16*)alloc((size_t)3456 * 1152 * 2);   //  8.0 MB
  _Float16* ow16   = (_Float16*)alloc((size_t)1152 * 1152 * 2);   //  2.7 MB
  _Float16* q16    = (_Float16*)alloc((size_t)256 * SP * QSTR * 2); // 40.9 MB
  _Float16* k16    = (_Float16*)alloc((size_t)256 * SP * QSTR * 2); // 40.9 MB
  _Float16* vT16   = (_Float16*)alloc((size_t)256 * HDP * SP * 2);  // 37.7 MB
  _Float16* pv16   = (_Float16*)alloc((size_t)M1 * D_ * 2);       // 26.9 MB

  // zero padded buffers (pads must be exactly 0 for masked-free math)
  hipMemsetAsync(q16,  0, (size_t)256 * SP * QSTR * 2, stream);
  hipMemsetAsync(k16,  0, (size_t)256 * SP * QSTR * 2, stream);
  hipMemsetAsync(vT16, 0, (size_t)256 * HDP * SP * 2, stream);

  // f32 -> f16 conversions
  cvt_f32_f16<<<2048, 256, 0, stream>>>(hs, h16, M1 * D_ / 4);
  cvt_f32_f16<<<512, 256, 0, stream>>>(qw, wqkv16,                 1152 * 1152 / 4);
  cvt_f32_f16<<<512, 256, 0, stream>>>(kw, wqkv16 + 1152 * 1152,   1152 * 1152 / 4);
  cvt_f32_f16<<<512, 256, 0, stream>>>(vw, wqkv16 + 2 * 1152 * 1152, 1152 * 1152 / 4);
  cvt_f32_f16<<<512, 256, 0, stream>>>(ow, ow16, 1152 * 1152 / 4);

  // QKV projection: 27 col-tiles x 92 row-tiles
  gemm_qkv<<<dim3(27, 92), 256, 0, stream>>>(h16, wqkv16, qb, kb, vb, q16, k16, vT16);

  // fused attention: 23 row-blocks x 256 (b,h)
  float* attn_out = (float*)d_out + (size_t)M1 * D_;   // 13,436,928
  attn_fused<<<dim3(23, 256), 256, 0, stream>>>(q16, k16, vT16, attn_out, pv16);

  // output projection: 9 col-tiles x 92 row-tiles
  gemm_out<<<dim3(9, 92), 256, 0, stream>>>(pv16, ow16, ob, (float*)d_out);
}

// Round 2
// 1372.950 us; speedup vs baseline: 1.1406x; 1.1406x over previous
//
#include <hip/hip_runtime.h>
#include <cstdint>
#include <cstddef>

typedef _Float16 half8 __attribute__((ext_vector_type(8)));
typedef _Float16 half4 __attribute__((ext_vector_type(4)));
typedef float    f32x4 __attribute__((ext_vector_type(4)));
typedef float    f32x4_u __attribute__((ext_vector_type(4), aligned(4)));
typedef float    fvec4 __attribute__((ext_vector_type(4)));

#define DEV __device__ __forceinline__

constexpr int S_  = 729;
constexpr int D_  = 1152;
constexpr int H_  = 16;
constexpr int HD_ = 72;
constexpr int B_  = 16;
constexpr int M1  = B_ * S_;       // 11664
constexpr int SP  = 768;           // padded sequence
constexpr int HDP = 96;            // padded head dim (3 x K=32)
constexpr int QSTR = 104;          // row stride (f16) of q16/k16 (2-way-conflict-free)
constexpr float SCALE = 0.11785113019775793f;  // 72^-0.5

// ---- async global->LDS, 16B per lane -------------------------------------
DEV void gload16(const void* g, void* l) {
  typedef const __attribute__((address_space(1))) unsigned int GU;
  typedef __attribute__((address_space(3))) unsigned int LU;
  __builtin_amdgcn_global_load_lds((GU*)g, (LU*)l, 16, 0, 0);
}

DEV void fence_mem() { asm volatile("" ::: "memory"); }

// ---- f32 -> f16 conversion (vectorized) ----------------------------------
__global__ void cvt_f32_f16(const float* __restrict__ src, _Float16* __restrict__ dst, int n4) {
  int stride = gridDim.x * blockDim.x;
  for (int i = blockIdx.x * blockDim.x + threadIdx.x; i < n4; i += stride) {
    fvec4 v = ((const fvec4*)src)[i];
    half4 o;
    o[0] = (_Float16)v[0]; o[1] = (_Float16)v[1];
    o[2] = (_Float16)v[2]; o[3] = (_Float16)v[3];
    ((half4*)dst)[i] = o;
  }
}

// ---- K1: fused QKV projection GEMM  (M=11664, N=3456, K=1152) ------------
__global__ __launch_bounds__(256) void gemm_qkv(
    const _Float16* __restrict__ A, const _Float16* __restrict__ W,
    const float* __restrict__ qb, const float* __restrict__ kb, const float* __restrict__ vb,
    _Float16* __restrict__ q16, _Float16* __restrict__ k16, _Float16* __restrict__ vT16)
{
  __shared__ _Float16 lA[128 * 32];
  __shared__ _Float16 lB[128 * 32];
  const int tid  = threadIdx.x;
  const int wave = tid >> 6, lane = tid & 63;
  const int wr = wave >> 1, wc = wave & 1;
  const int l15 = lane & 15, l4 = lane >> 4;
  const int rowBase = blockIdx.y * 128;
  const int colBase = blockIdx.x * 128;

  f32x4 acc[4][4] = {};

  for (int kt = 0; kt < 36; ++kt) {
#pragma unroll
    for (int p = 0; p < 2; ++p) {
      int u = p * 256 + tid;
      int r = u >> 2, q = u & 3;
      int row = rowBase + r; if (row > M1 - 1) row = M1 - 1;   // tail clamp
      gload16(A + ((size_t)row * 1152 + kt * 32 + q * 8), &lA[u * 8]);
      gload16(W + ((size_t)(colBase + r) * 1152 + kt * 32 + q * 8), &lB[u * 8]);
    }
    __syncthreads();
    half8 af[4], bf[4];
#pragma unroll
    for (int i = 0; i < 4; ++i) {
      af[i] = *(const half8*)&lA[(wr * 64 + i * 16 + l15) * 32 + l4 * 8];
      bf[i] = *(const half8*)&lB[(wc * 64 + i * 16 + l15) * 32 + l4 * 8];
    }
#pragma unroll
    for (int mi = 0; mi < 4; ++mi)
#pragma unroll
      for (int ni = 0; ni < 4; ++ni)
        acc[mi][ni] = __builtin_amdgcn_mfma_f32_16x16x32_f16(af[mi], bf[ni], acc[mi][ni], 0, 0, 0);
    __syncthreads();
  }

  const int which = colBase / 1152;                 // 0=q 1=k 2=v
  const int wi0 = colBase - which * 1152 + wc * 64;
  const float* bias = (which == 0) ? qb : (which == 1) ? kb : vb;
#pragma unroll
  for (int ni = 0; ni < 4; ++ni) {
    int wi = wi0 + ni * 16 + l15;
    int hh = wi / 72;
    int dd = wi - hh * 72;
    float bv = bias[wi];
#pragma unroll
    for (int mi = 0; mi < 4; ++mi) {
#pragma unroll
      for (int reg = 0; reg < 4; ++reg) {
        int m = rowBase + wr * 64 + mi * 16 + l4 * 4 + reg;
        if (m < M1) {
          float val = acc[mi][ni][reg] + bv;
          int b = m / 729;
          int s = m - b * 729;
          int bh = b * 16 + hh;
          if (which == 0)      q16[((size_t)bh * SP + s) * QSTR + dd] = (_Float16)val;
          else if (which == 1) k16[((size_t)bh * SP + s) * QSTR + dd] = (_Float16)val;
          else                 vT16[((size_t)bh * HDP + dd) * SP + s] = (_Float16)val;
        }
      }
    }
  }
}

// ---- K2 v2: 512-thread fused attention -----------------------------------
// dbuf K staging (counted vmcnt + raw barriers), 1 exp pass, 8-wave PV,
// XCD-bijective block swizzle.
DEV void stageK(const _Float16* src, _Float16* dst, int wv, int lane) {
  // 26 chunks of 1KB per 128x104 f16 tile; wave w takes chunks w, w+8, ...
  for (int c = wv; c < 26; c += 8)
    gload16((const char*)src + c * 1024 + lane * 16, (char*)dst + c * 1024 + lane * 16);
}

__global__ __launch_bounds__(512) void attn_fused(
    const _Float16* __restrict__ q16, const _Float16* __restrict__ k16,
    const _Float16* __restrict__ vT16,
    float* __restrict__ attnOut,          // [256][729][729]
    _Float16* __restrict__ pv16)          // [M1][1152]
{
  __shared__ __align__(16) _Float16 sQ[32 * QSTR];        // 6656 B
  __shared__ __align__(16) _Float16 sKb[2][128 * QSTR];   // 53248 B
  __shared__ __align__(16) float    sS[32 * 772];         // 98816 B
  __shared__ float sL[32];
  float* red = (float*)&sKb[0][0];                        // 12288 B overlay (sK dead in PV)

  const int tid  = threadIdx.x;
  const int wv   = tid >> 6, lane = tid & 63;
  const int l15  = lane & 15, l4 = lane >> 4;

  // XCD-bijective swizzle: nwg = 23*256 = 5888 = 8*736; XCD x gets bh chunk of 32
  const int lin  = blockIdx.y * 23 + blockIdx.x;
  const int nlin = (lin & 7) * 736 + (lin >> 3);
  const int bh   = nlin / 23;
  const int rb   = nlin - bh * 23;

  const _Float16* Qg = q16 + ((size_t)bh * SP + rb * 32) * QSTR;
  const _Float16* Kg = k16 + (size_t)bh * SP * QSTR;
  const _Float16* Vg = vT16 + (size_t)bh * HDP * SP;

  // ---- prologue: stage Q (reg path) + K tile 0 ----
  if (tid < 416) {
    half8 v = *(const half8*)(Qg + tid * 8);
    *(half8*)(sQ + tid * 8) = v;
  }
  stageK(Kg, sKb[0], wv, lane);
  __syncthreads();   // full drain: buf0 + Q resident

  // ---- QK^T: 6 tiles of 128 cols, double-buffered ----
  for (int ct = 0; ct < 6; ++ct) {
    const _Float16* cur = sKb[ct & 1];
    if (ct < 5) {
      stageK(Kg + (ct + 1) * (128 * QSTR), sKb[(ct + 1) & 1], wv, lane);
      if (wv < 2) asm volatile("s_waitcnt vmcnt(4)" ::: "memory");
      else        asm volatile("s_waitcnt vmcnt(3)" ::: "memory");
    } else {
      asm volatile("s_waitcnt vmcnt(0)" ::: "memory");
    }
    __builtin_amdgcn_s_barrier();   // all waves' current-tile chunks resident
    fence_mem();

    f32x4 acc0 = {0.f, 0.f, 0.f, 0.f};
    f32x4 acc1 = {0.f, 0.f, 0.f, 0.f};
#pragma unroll
    for (int kk = 0; kk < 3; ++kk) {
      half8 a0 = *(const half8*)&sQ[(l15) * QSTR + kk * 32 + l4 * 8];
      half8 a1 = *(const half8*)&sQ[(16 + l15) * QSTR + kk * 32 + l4 * 8];
      half8 b  = *(const half8*)&cur[(wv * 16 + l15) * QSTR + kk * 32 + l4 * 8];
      acc0 = __builtin_amdgcn_mfma_f32_16x16x32_f16(a0, b, acc0, 0, 0, 0);
      acc1 = __builtin_amdgcn_mfma_f32_16x16x32_f16(a1, b, acc1, 0, 0, 0);
    }
#pragma unroll
    for (int r = 0; r < 4; ++r) {
      sS[(l4 * 4 + r) * 772 + ct * 128 + wv * 16 + l15]        = acc0[r] * SCALE;
      sS[(16 + l4 * 4 + r) * 772 + ct * 128 + wv * 16 + l15]   = acc1[r] * SCALE;
    }
    asm volatile("s_waitcnt lgkmcnt(0)" ::: "memory");
    __builtin_amdgcn_s_barrier();   // protect buf reuse; sS visible (vm loads stay in flight)
    fence_mem();
  }

  // ---- softmax stats + in-place e = exp(s - m): 16 lanes per row ----
  const int sr = tid >> 4, sj = tid & 15;
  float m = -1e30f;
  for (int c = sj; c < 729; c += 16) m = fmaxf(m, sS[sr * 772 + c]);
#pragma unroll
  for (int o = 1; o < 16; o <<= 1) m = fmaxf(m, __shfl_xor(m, o));
  float sum = 0.f;
  for (int c = sj; c < 768; c += 16) {
    float s = sS[sr * 772 + c];
    float e = (c < 729) ? __expf(s - m) : 0.f;
    sS[sr * 772 + c] = e;
    sum += e;
  }
#pragma unroll
  for (int o = 1; o < 16; o <<= 1) sum += __shfl_xor(sum, o);
  const float rl = 1.0f / sum;
  if (sj == 0) sL[sr] = rl;
  __syncthreads();

  // ---- attn output stores (issue first; drain under PV) ----
  {
    const int grow = rb * 32 + sr;
    float* aout = attnOut + (size_t)bh * 531441 + (size_t)grow * 729;
    if (grow < 729) {
#pragma unroll
      for (int it = 0; it < 12; ++it) {
        int c4 = sj + it * 16;
        if (c4 < 182) {
          f32x4 e = *(const f32x4*)&sS[sr * 772 + c4 * 4];
          f32x4 p = e * rl;
          *(f32x4_u*)&aout[c4 * 4] = p;
        }
      }
      if (sj == 6) aout[728] = sS[sr * 772 + 728] * rl;
    }
  }

  // ---- PV: 8 waves = 2 row-halves x 2 col-halves x 2 K-halves ----
  const int wm = wv >> 2, wn = (wv >> 1) & 1, kh = wv & 1;
  f32x4 pacc[3] = {};
  const _Float16* Vw = Vg + (size_t)wn * 48 * SP;
  for (int kk = kh * 12; kk < kh * 12 + 12; ++kk) {
    const float* sp = &sS[(wm * 16 + l15) * 772 + kk * 32 + l4 * 8];
    f32x4 e0 = *(const f32x4*)sp;
    f32x4 e1 = *(const f32x4*)(sp + 4);
    half8 a;
    a[0] = (_Float16)e0[0]; a[1] = (_Float16)e0[1];
    a[2] = (_Float16)e0[2]; a[3] = (_Float16)e0[3];
    a[4] = (_Float16)e1[0]; a[5] = (_Float16)e1[1];
    a[6] = (_Float16)e1[2]; a[7] = (_Float16)e1[3];
#pragma unroll
    for (int f = 0; f < 3; ++f) {
      half8 bv = *(const half8*)&Vw[(size_t)(f * 16 + l15) * SP + kk * 32 + l4 * 8];
      pacc[f] = __builtin_amdgcn_mfma_f32_16x16x32_f16(a, bv, pacc[f], 0, 0, 0);
    }
  }
  const int unit = wv >> 1;
  if (kh == 1) {
#pragma unroll
    for (int f = 0; f < 3; ++f)
      *(f32x4*)&red[((unit * 3 + f) * 64 + lane) * 4] = pacc[f];
  }
  __syncthreads();
  if (kh == 0) {
    const int b = bh >> 4, h = bh & 15;
#pragma unroll
    for (int f = 0; f < 3; ++f) {
      f32x4 o = pacc[f] + *(const f32x4*)&red[((unit * 3 + f) * 64 + lane) * 4];
      int dd = wn * 48 + f * 16 + l15;
#pragma unroll
      for (int r = 0; r < 4; ++r) {
        int row  = wm * 16 + l4 * 4 + r;
        int srow = rb * 32 + row;
        if (dd < HD_ && srow < S_) {
          float val = o[r] * sL[row];
          pv16[((size_t)(b * 729 + srow)) * 1152 + h * 72 + dd] = (_Float16)val;
        }
      }
    }
  }
}

// ---- K3: output projection GEMM (M=11664, N=1152, K=1152) -> fp32 out ----
__global__ __launch_bounds__(256) void gemm_out(
    const _Float16* __restrict__ A, const _Float16* __restrict__ W,
    const float* __restrict__ ob, float* __restrict__ Cout)
{
  __shared__ _Float16 lA[128 * 32];
  __shared__ _Float16 lB[128 * 32];
  const int tid  = threadIdx.x;
  const int wave = tid >> 6, lane = tid & 63;
  const int wr = wave >> 1, wc = wave & 1;
  const int l15 = lane & 15, l4 = lane >> 4;
  const int rowBase = blockIdx.y * 128;
  const int colBase = blockIdx.x * 128;

  f32x4 acc[4][4] = {};

  for (int kt = 0; kt < 36; ++kt) {
#pragma unroll
    for (int p = 0; p < 2; ++p) {
      int u = p * 256 + tid;
      int r = u >> 2, q = u & 3;
      int row = rowBase + r; if (row > M1 - 1) row = M1 - 1;
      gload16(A + ((size_t)row * 1152 + kt * 32 + q * 8), &lA[u * 8]);
      gload16(W + ((size_t)(colBase + r) * 1152 + kt * 32 + q * 8), &lB[u * 8]);
    }
    __syncthreads();
    half8 af[4], bf[4];
#pragma unroll
    for (int i = 0; i < 4; ++i) {
      af[i] = *(const half8*)&lA[(wr * 64 + i * 16 + l15) * 32 + l4 * 8];
      bf[i] = *(const half8*)&lB[(wc * 64 + i * 16 + l15) * 32 + l4 * 8];
    }
#pragma unroll
    for (int mi = 0; mi < 4; ++mi)
#pragma unroll
      for (int ni = 0; ni < 4; ++ni)
        acc[mi][ni] = __builtin_amdgcn_mfma_f32_16x16x32_f16(af[mi], bf[ni], acc[mi][ni], 0, 0, 0);
    __syncthreads();
  }

#pragma unroll
  for (int ni = 0; ni < 4; ++ni) {
    int n = colBase + wc * 64 + ni * 16 + l15;
    float bv = ob[n];
#pragma unroll
    for (int mi = 0; mi < 4; ++mi) {
#pragma unroll
      for (int reg = 0; reg < 4; ++reg) {
        int m = rowBase + wr * 64 + mi * 16 + l4 * 4 + reg;
        if (m < M1) Cout[(size_t)m * 1152 + n] = acc[mi][ni][reg] + bv;
      }
    }
  }
}

// --------------------------------------------------------------------------
extern "C" void kernel_launch(void* const* d_in, const int* in_sizes, int n_in,
                              void* d_out, int out_size, void* d_ws, size_t ws_size,
                              hipStream_t stream) {
  const float* hs = (const float*)d_in[0];
  const float* qw = (const float*)d_in[1];
  const float* qb = (const float*)d_in[2];
  const float* kw = (const float*)d_in[3];
  const float* kb = (const float*)d_in[4];
  const float* vw = (const float*)d_in[5];
  const float* vb = (const float*)d_in[6];
  const float* ow = (const float*)d_in[7];
  const float* ob = (const float*)d_in[8];

  char* ws = (char*)d_ws;
  size_t off = 0;
  auto alloc = [&](size_t bytes) {
    char* p = ws + off;
    off = (off + bytes + 255) & ~(size_t)255;
    return p;
  };
  _Float16* h16    = (_Float16*)alloc((size_t)M1 * D_ * 2);
  _Float16* wqkv16 = (_Float16*)alloc((size_t)3456 * 1152 * 2);
  _Float16* ow16   = (_Float16*)alloc((size_t)1152 * 1152 * 2);
  _Float16* q16    = (_Float16*)alloc((size_t)256 * SP * QSTR * 2);
  _Float16* k16    = (_Float16*)alloc((size_t)256 * SP * QSTR * 2);
  _Float16* vT16   = (_Float16*)alloc((size_t)256 * HDP * SP * 2);
  _Float16* pv16   = (_Float16*)alloc((size_t)M1 * D_ * 2);

  hipMemsetAsync(q16,  0, (size_t)256 * SP * QSTR * 2, stream);
  hipMemsetAsync(k16,  0, (size_t)256 * SP * QSTR * 2, stream);
  hipMemsetAsync(vT16, 0, (size_t)256 * HDP * SP * 2, stream);

  cvt_f32_f16<<<2048, 256, 0, stream>>>(hs, h16, M1 * D_ / 4);
  cvt_f32_f16<<<512, 256, 0, stream>>>(qw, wqkv16,                   1152 * 1152 / 4);
  cvt_f32_f16<<<512, 256, 0, stream>>>(kw, wqkv16 + 1152 * 1152,     1152 * 1152 / 4);
  cvt_f32_f16<<<512, 256, 0, stream>>>(vw, wqkv16 + 2 * 1152 * 1152, 1152 * 1152 / 4);
  cvt_f32_f16<<<512, 256, 0, stream>>>(ow, ow16, 1152 * 1152 / 4);

  gemm_qkv<<<dim3(27, 92), 256, 0, stream>>>(h16, wqkv16, qb, kb, vb, q16, k16, vT16);

  float* attn_out = (float*)d_out + (size_t)M1 * D_;
  attn_fused<<<dim3(23, 256), 512, 0, stream>>>(q16, k16, vT16, attn_out, pv16);

  gemm_out<<<dim3(9, 92), 256, 0, stream>>>(pv16, ow16, ob, (float*)d_out);
}

// Round 5
// 1337.849 us; speedup vs baseline: 1.1706x; 1.0262x over previous
//
#include <hip/hip_runtime.h>
#include <cstdint>
#include <cstddef>

typedef _Float16 half8 __attribute__((ext_vector_type(8)));
typedef _Float16 half4 __attribute__((ext_vector_type(4)));
typedef float    f32x4 __attribute__((ext_vector_type(4)));
typedef float    f32x4_u __attribute__((ext_vector_type(4), aligned(4)));
typedef float    fvec4 __attribute__((ext_vector_type(4)));

#define DEV __device__ __forceinline__

constexpr int S_  = 729;
constexpr int D_  = 1152;
constexpr int H_  = 16;
constexpr int HD_ = 72;
constexpr int B_  = 16;
constexpr int M1  = B_ * S_;       // 11664
constexpr int SP  = 768;           // padded sequence
constexpr int HDP = 96;            // padded head dim
constexpr int QSTR = 104;          // row stride (f16) of q16/k16
constexpr float SCALE = 0.11785113019775793f;  // 72^-0.5

// ---- async global->LDS, 16B per lane -------------------------------------
DEV void gload16(const void* g, void* l) {
  typedef const __attribute__((address_space(1))) unsigned int GU;
  typedef __attribute__((address_space(3))) unsigned int LU;
  __builtin_amdgcn_global_load_lds((GU*)g, (LU*)l, 16, 0, 0);
}

// ---- f32 -> f16 conversion (vectorized) ----------------------------------
__global__ void cvt_f32_f16(const float* __restrict__ src, _Float16* __restrict__ dst, int n4) {
  int stride = gridDim.x * blockDim.x;
  for (int i = blockIdx.x * blockDim.x + threadIdx.x; i < n4; i += stride) {
    fvec4 v = ((const fvec4*)src)[i];
    half4 o;
    o[0] = (_Float16)v[0]; o[1] = (_Float16)v[1];
    o[2] = (_Float16)v[2]; o[3] = (_Float16)v[3];
    ((half4*)dst)[i] = o;
  }
}

// ---- K1: fused QKV projection GEMM  (M=11664, N=3456, K=1152) ------------
__global__ __launch_bounds__(256) void gemm_qkv(
    const _Float16* __restrict__ A, const _Float16* __restrict__ W,
    const float* __restrict__ qb, const float* __restrict__ kb, const float* __restrict__ vb,
    _Float16* __restrict__ q16, _Float16* __restrict__ k16, _Float16* __restrict__ vT16)
{
  __shared__ _Float16 lA[128 * 32];
  __shared__ _Float16 lB[128 * 32];
  const int tid  = threadIdx.x;
  const int wave = tid >> 6, lane = tid & 63;
  const int wr = wave >> 1, wc = wave & 1;
  const int l15 = lane & 15, l4 = lane >> 4;
  const int rowBase = blockIdx.y * 128;
  const int colBase = blockIdx.x * 128;

  f32x4 acc[4][4] = {};

  for (int kt = 0; kt < 36; ++kt) {
#pragma unroll
    for (int p = 0; p < 2; ++p) {
      int u = p * 256 + tid;
      int r = u >> 2, q = u & 3;
      int row = rowBase + r; if (row > M1 - 1) row = M1 - 1;   // tail clamp
      gload16(A + ((size_t)row * 1152 + kt * 32 + q * 8), &lA[u * 8]);
      gload16(W + ((size_t)(colBase + r) * 1152 + kt * 32 + q * 8), &lB[u * 8]);
    }
    __syncthreads();
    half8 af[4], bf[4];
#pragma unroll
    for (int i = 0; i < 4; ++i) {
      af[i] = *(const half8*)&lA[(wr * 64 + i * 16 + l15) * 32 + l4 * 8];
      bf[i] = *(const half8*)&lB[(wc * 64 + i * 16 + l15) * 32 + l4 * 8];
    }
#pragma unroll
    for (int mi = 0; mi < 4; ++mi)
#pragma unroll
      for (int ni = 0; ni < 4; ++ni)
        acc[mi][ni] = __builtin_amdgcn_mfma_f32_16x16x32_f16(af[mi], bf[ni], acc[mi][ni], 0, 0, 0);
    __syncthreads();
  }

  const int which = colBase / 1152;                 // 0=q 1=k 2=v
  const int wi0 = colBase - which * 1152 + wc * 64;
  const float* bias = (which == 0) ? qb : (which == 1) ? kb : vb;
#pragma unroll
  for (int ni = 0; ni < 4; ++ni) {
    int wi = wi0 + ni * 16 + l15;
    int hh = wi / 72;
    int dd = wi - hh * 72;
    float bv = bias[wi];
#pragma unroll
    for (int mi = 0; mi < 4; ++mi) {
#pragma unroll
      for (int reg = 0; reg < 4; ++reg) {
        int m = rowBase + wr * 64 + mi * 16 + l4 * 4 + reg;
        if (m < M1) {
          float val = acc[mi][ni][reg] + bv;
          int b = m / 729;
          int s = m - b * 729;
          int bh = b * 16 + hh;
          if (which == 0)      q16[((size_t)bh * SP + s) * QSTR + dd] = (_Float16)val;
          else if (which == 1) k16[((size_t)bh * SP + s) * QSTR + dd] = (_Float16)val;
          else                 vT16[((size_t)bh * HDP + dd) * SP + s] = (_Float16)val;
        }
      }
    }
  }
}

// ---- K2 v3: register-resident fused attention ----------------------------
// Swapped QK^T (S^T in regs), in-reg softmax, PV via 16x16x16 with zero
// repack, K/V frags straight from L2 (no LDS staging), 2 barriers total.
// grid: x = 48 row-blocks of 16 q-rows, y = 256 (b*16+h); XCD swizzle.
__global__ __launch_bounds__(256, 4) void attn_fused(
    const _Float16* __restrict__ q16, const _Float16* __restrict__ k16,
    const _Float16* __restrict__ vT16,
    float* __restrict__ attnOut,          // [256][729][729]
    _Float16* __restrict__ pv16)          // [M1][1152]
{
  __shared__ __align__(16) float sRed[3][16][80];   // kq 1..3 partial O^T [q][d] : 15 KB
  __shared__ float sStat[4][16][2];                 // per-kq (m,l) per q row

  const int tid  = threadIdx.x;
  const int wv   = tid >> 6, lane = tid & 63;       // wv = k-quarter (192 k each)
  const int l15  = lane & 15, l4 = lane >> 4;

  // XCD-bijective swizzle: 12288 blocks = 8 * 1536; all 48 blocks of a bh on one XCD
  const int lin  = blockIdx.y * 48 + blockIdx.x;
  const int nlin = (lin & 7) * 1536 + (lin >> 3);
  const int bh   = nlin / 48;
  const int rb   = nlin - bh * 48;
  const int q0   = rb * 16;

  const _Float16* Qg = q16 + ((size_t)bh * SP + q0) * QSTR;
  const _Float16* Kg = k16 + ((size_t)bh * SP + wv * 192) * QSTR;
  const _Float16* Vg = vT16 + (size_t)bh * HDP * SP + wv * 192;

  // Q b-frags: lane holds Q[q0+l15][d = dstep*32 + l4*8 .. +7]
  half8 qf[3];
#pragma unroll
  for (int d = 0; d < 3; ++d)
    qf[d] = *(const half8*)(Qg + (size_t)l15 * QSTR + d * 32 + l4 * 8);

  // ---- pass A: S^T tiles into registers; per-lane max ----
  float sc[12][4];
  float m_ln = -1e30f;
#pragma unroll
  for (int t = 0; t < 12; ++t) {
    f32x4 a = {0.f, 0.f, 0.f, 0.f};
#pragma unroll
    for (int d = 0; d < 3; ++d) {
      half8 kf = *(const half8*)(Kg + (size_t)(t * 16 + l15) * QSTR + d * 32 + l4 * 8);
      a = __builtin_amdgcn_mfma_f32_16x16x32_f16(kf, qf[d], a, 0, 0, 0);
    }
#pragma unroll
    for (int r = 0; r < 4; ++r) {
      int kidx = wv * 192 + t * 16 + l4 * 4 + r;
      float s = (kidx < S_) ? a[r] * SCALE : -1e30f;
      sc[t][r] = s;
      m_ln = fmaxf(m_ln, s);
    }
  }
  float l_ln = 0.f;
#pragma unroll
  for (int t = 0; t < 12; ++t)
#pragma unroll
    for (int r = 0; r < 4; ++r) l_ln += __expf(sc[t][r] - m_ln);

  // combine the 4 lanes sharing q (l ^ 16, l ^ 32)
#pragma unroll
  for (int o = 16; o < 64; o <<= 1) {
    float mo = __shfl_xor(m_ln, o), lo = __shfl_xor(l_ln, o);
    float M2 = fmaxf(m_ln, mo);
    l_ln = l_ln * __expf(m_ln - M2) + lo * __expf(mo - M2);
    m_ln = M2;
  }
  if (lane < 16) { sStat[wv][l15][0] = m_ln; sStat[wv][l15][1] = l_ln; }
  __syncthreads();

  // final (M, L) per q-row, computed redundantly by every lane (broadcast reads)
  float M = sStat[0][l15][0], L = sStat[0][l15][1];
#pragma unroll
  for (int k = 1; k < 4; ++k) {
    float mk = sStat[k][l15][0], lk = sStat[k][l15][1];
    float Mn = fmaxf(M, mk);
    L = L * __expf(M - Mn) + lk * __expf(mk - Mn);
    M = Mn;
  }
  const float rl = 1.0f / L;

  // ---- pass B: e = exp(s-M) once -> attn write + PV (O^T = V^T * P^T) ----
  const bool qvalid = (q0 + l15) < S_;
  float* arow = attnOut + (size_t)bh * 531441 + (size_t)(q0 + l15) * 729;

  f32x4 pacc[5] = {};
#pragma unroll
  for (int t = 0; t < 12; ++t) {
    int kbase = wv * 192 + t * 16 + l4 * 4;
    f32x4 e;
#pragma unroll
    for (int r = 0; r < 4; ++r) e[r] = __expf(sc[t][r] - M);

    if (qvalid) {
      if (kbase + 3 < S_) {
        f32x4 p = e * rl;
        *(f32x4_u*)(arow + kbase) = p;
      } else {
#pragma unroll
        for (int r = 0; r < 4; ++r)
          if (kbase + r < S_) arow[kbase + r] = e[r] * rl;
      }
    }

    half4 pb;
#pragma unroll
    for (int r = 0; r < 4; ++r) pb[r] = (_Float16)e[r];
#pragma unroll
    for (int dt = 0; dt < 5; ++dt) {   // d 0..79 (d>=72 is zero-pad V, masked at store)
      half4 vf = *(const half4*)(Vg + (size_t)(dt * 16 + l15) * SP + t * 16 + l4 * 4);
      pacc[dt] = __builtin_amdgcn_mfma_f32_16x16x16f16(vf, pb, pacc[dt], 0, 0, 0);
    }
  }

  // ---- 4-way k-quarter reduction via LDS; wave 0 finalizes ----
  if (wv > 0) {
#pragma unroll
    for (int dt = 0; dt < 5; ++dt)
      *(f32x4*)&sRed[wv - 1][l15][dt * 16 + l4 * 4] = pacc[dt];
  }
  __syncthreads();
  if (wv == 0) {
    const int b = bh >> 4, h = bh & 15;
#pragma unroll
    for (int dt = 0; dt < 5; ++dt) {
      f32x4 o = pacc[dt];
#pragma unroll
      for (int w = 0; w < 3; ++w)
        o += *(const f32x4*)&sRed[w][l15][dt * 16 + l4 * 4];
      int dbase = dt * 16 + l4 * 4;
      if (qvalid && dbase < HD_) {
        half4 ov;
#pragma unroll
        for (int r = 0; r < 4; ++r) ov[r] = (_Float16)(o[r] * rl);
        *(half4*)(pv16 + (size_t)(b * 729 + q0 + l15) * 1152 + h * 72 + dbase) = ov;
      }
    }
  }
}

// ---- K3: output projection GEMM (M=11664, N=1152, K=1152) -> fp32 out ----
__global__ __launch_bounds__(256) void gemm_out(
    const _Float16* __restrict__ A, const _Float16* __restrict__ W,
    const float* __restrict__ ob, float* __restrict__ Cout)
{
  __shared__ _Float16 lA[128 * 32];
  __shared__ _Float16 lB[128 * 32];
  const int tid  = threadIdx.x;
  const int wave = tid >> 6, lane = tid & 63;
  const int wr = wave >> 1, wc = wave & 1;
  const int l15 = lane & 15, l4 = lane >> 4;
  const int rowBase = blockIdx.y * 128;
  const int colBase = blockIdx.x * 128;

  f32x4 acc[4][4] = {};

  for (int kt = 0; kt < 36; ++kt) {
#pragma unroll
    for (int p = 0; p < 2; ++p) {
      int u = p * 256 + tid;
      int r = u >> 2, q = u & 3;
      int row = rowBase + r; if (row > M1 - 1) row = M1 - 1;
      gload16(A + ((size_t)row * 1152 + kt * 32 + q * 8), &lA[u * 8]);
      gload16(W + ((size_t)(colBase + r) * 1152 + kt * 32 + q * 8), &lB[u * 8]);
    }
    __syncthreads();
    half8 af[4], bf[4];
#pragma unroll
    for (int i = 0; i < 4; ++i) {
      af[i] = *(const half8*)&lA[(wr * 64 + i * 16 + l15) * 32 + l4 * 8];
      bf[i] = *(const half8*)&lB[(wc * 64 + i * 16 + l15) * 32 + l4 * 8];
    }
#pragma unroll
    for (int mi = 0; mi < 4; ++mi)
#pragma unroll
      for (int ni = 0; ni < 4; ++ni)
        acc[mi][ni] = __builtin_amdgcn_mfma_f32_16x16x32_f16(af[mi], bf[ni], acc[mi][ni], 0, 0, 0);
    __syncthreads();
  }

#pragma unroll
  for (int ni = 0; ni < 4; ++ni) {
    int n = colBase + wc * 64 + ni * 16 + l15;
    float bv = ob[n];
#pragma unroll
    for (int mi = 0; mi < 4; ++mi) {
#pragma unroll
      for (int reg = 0; reg < 4; ++reg) {
        int m = rowBase + wr * 64 + mi * 16 + l4 * 4 + reg;
        if (m < M1) Cout[(size_t)m * 1152 + n] = acc[mi][ni][reg] + bv;
      }
    }
  }
}

// --------------------------------------------------------------------------
extern "C" void kernel_launch(void* const* d_in, const int* in_sizes, int n_in,
                              void* d_out, int out_size, void* d_ws, size_t ws_size,
                              hipStream_t stream) {
  const float* hs = (const float*)d_in[0];
  const float* qw = (const float*)d_in[1];
  const float* qb = (const float*)d_in[2];
  const float* kw = (const float*)d_in[3];
  const float* kb = (const float*)d_in[4];
  const float* vw = (const float*)d_in[5];
  const float* vb = (const float*)d_in[6];
  const float* ow = (const float*)d_in[7];
  const float* ob = (const float*)d_in[8];

  char* ws = (char*)d_ws;
  size_t off = 0;
  auto alloc = [&](size_t bytes) {
    char* p = ws + off;
    off = (off + bytes + 255) & ~(size_t)255;
    return p;
  };
  _Float16* h16    = (_Float16*)alloc((size_t)M1 * D_ * 2);
  _Float16* wqkv16 = (_Float16*)alloc((size_t)3456 * 1152 * 2);
  _Float16* ow16   = (_Float16*)alloc((size_t)1152 * 1152 * 2);
  _Float16* q16    = (_Float16*)alloc((size_t)256 * SP * QSTR * 2);
  _Float16* k16    = (_Float16*)alloc((size_t)256 * SP * QSTR * 2);
  _Float16* vT16   = (_Float16*)alloc((size_t)256 * HDP * SP * 2);
  _Float16* pv16   = (_Float16*)alloc((size_t)M1 * D_ * 2);

  // zero padded buffers (d-pads inside valid rows must be 0; padded q rows must be 0)
  (void)hipMemsetAsync(q16,  0, (size_t)256 * SP * QSTR * 2, stream);
  (void)hipMemsetAsync(k16,  0, (size_t)256 * SP * QSTR * 2, stream);
  (void)hipMemsetAsync(vT16, 0, (size_t)256 * HDP * SP * 2, stream);

  cvt_f32_f16<<<2048, 256, 0, stream>>>(hs, h16, M1 * D_ / 4);
  cvt_f32_f16<<<512, 256, 0, stream>>>(qw, wqkv16,                   1152 * 1152 / 4);
  cvt_f32_f16<<<512, 256, 0, stream>>>(kw, wqkv16 + 1152 * 1152,     1152 * 1152 / 4);
  cvt_f32_f16<<<512, 256, 0, stream>>>(vw, wqkv16 + 2 * 1152 * 1152, 1152 * 1152 / 4);
  cvt_f32_f16<<<512, 256, 0, stream>>>(ow, ow16, 1152 * 1152 / 4);

  gemm_qkv<<<dim3(27, 92), 256, 0, stream>>>(h16, wqkv16, qb, kb, vb, q16, k16, vT16);

  float* attn_out = (float*)d_out + (size_t)M1 * D_;
  attn_fused<<<dim3(48, 256), 256, 0, stream>>>(q16, k16, vT16, attn_out, pv16);

  gemm_out<<<dim3(9, 92), 256, 0, stream>>>(pv16, ow16, ob, (float*)d_out);
}